// Round 9
// baseline (186.467 us; speedup 1.0000x reference)
//
#include <hip/hip_runtime.h>
#include <hip/hip_bf16.h>

#define BB 16
#define NN 64
#define PREVN 6
#define PREDN 30
#define HH 256
#define EE 4032              // NN*(NN-1)
#define EROWS (BB*EE)        // 64512
#define NROWS (BB*NN)        // 1024
#define RSE 32               // edge-stats replicas
#define RSM 16               // node-stats replicas

typedef short short8 __attribute__((ext_vector_type(8)));
typedef float f32x4 __attribute__((ext_vector_type(4)));

// ---- f32 workspace layout (float element offsets) ----
enum : int {
  OFF_STATS_E = 0,       // RSE replicas x [512]: [0:256]=sum [256:512]=sumsq
  OFF_STATS_M = 16384,   // RSM replicas x [512]
  OFF_XRS     = 32768,   // 262144 f32 slots = 524288 bf16: XR ++ XS
  F32_END     = 294912
};
// ---- bf16 area (element offsets within wb = (bf16*)(ws + F32_END)) ----
// Weight panels in MFMA-fragment order:
//   P[((j*KC + ks)*64 + lane)*8 + e] = W[ks*32 + (lane>>4)*8 + e][j*16 + (lane&15)]
enum : size_t {
  BO_W1TE  = 0,          // 256*512 (n2e W1 panel, KC=16)
  BO_W2TE  = 131072,     // 256*256 (n2e W2 panel, KC=8)
  BO_W1TN  = 196608,     // 256*512 (e2n W1 panel, KC=16)
  BO_W2TN  = 327680,     // 256*256 (e2n W2 panel, KC=8)
  BO_WFT   = 393216,     // 256*512 (W_fuse panel, KC=16)
  BO_WPT   = 524288,     // 64*256  (W_pred panel, KC=8, cols 60..63 zero)
  BO_XG    = 540672,     // 1024*256 raw x (bf16)
  BO_NODES = 802816,     // 1024*512
  BO_H1G   = 1327104,    // 1024*256 node-MLP h1  (overlaid by incraw pre-k_n1)
  BO_M2    = 1589248,    // 1024*256
  BO_FG    = 1851392,    // 1024*256 fused
  BO_E2    = 2113536     // 64512*256 SENDER-major: row = (b*64+send)*63 + jpos
};
// incraw = (float*)(wb + BO_H1G): 1024x256 f32 (1 MB), dead before k_n1 runs.

// fast ELU: exp(x)-1 via v_exp_f32
__device__ __forceinline__ float eluf(float v) { return v > 0.f ? v : __expf(v) - 1.f; }

// compute one x-embed element: row rr (global), col
__device__ __forceinline__ float xembed(const float* __restrict__ centers,
                                        const float* __restrict__ Wt,
                                        const float* __restrict__ bt,
                                        int rr, int col) {
  const float* c = centers + rr * 12;
  float acc = bt[col];
  #pragma unroll
  for (int t = 0; t < 5; ++t) {
    float dx = c[(t+1)*2 + 0] - c[t*2 + 0];
    float dy = c[(t+1)*2 + 1] - c[t*2 + 1];
    acc += dx * Wt[(2 + 2*t)*HH + col] + dy * Wt[(3 + 2*t)*HH + col];
  }
  return acc;
}

// ================= prep: weight panels + zero stats/incraw + x-embed ===========
struct PrepArgs {
  const float *centers, *W_traj, *b_traj;
  const float *n2e_W1, *n2e_W2, *e2n_W1, *e2n_W2, *W_fuse, *W_pred;
  float* ws;
  float* inc;                      // incraw 1024x256 f32
  __hip_bfloat16 *p1e, *p2e, *p1n, *p2n, *pf, *pp, *xg;
};

__global__ __launch_bounds__(256) void k_prep(PrepArgs a) {
  const int bid = blockIdx.x, tid = threadIdx.x;
  if (bid < 264) {                 // weight panels, 4 tiles (1KB each) per block
    const float* W; __hip_bfloat16* P; int ksh, t0, pad = 0;
    if (bid < 64)       { W = a.n2e_W1; P = a.p1e; ksh = 4; t0 = bid*4; }
    else if (bid < 96)  { W = a.n2e_W2; P = a.p2e; ksh = 3; t0 = (bid-64)*4; }
    else if (bid < 160) { W = a.e2n_W1; P = a.p1n; ksh = 4; t0 = (bid-96)*4; }
    else if (bid < 192) { W = a.e2n_W2; P = a.p2n; ksh = 3; t0 = (bid-160)*4; }
    else if (bid < 256) { W = a.W_fuse; P = a.pf;  ksh = 4; t0 = (bid-192)*4; }
    else                { W = a.W_pred; P = a.pp;  ksh = 3; t0 = (bid-256)*4; pad = 1; }
    const int l = tid & 63, sub = tid >> 6;
    const int t = t0 + sub;
    const int j = t >> ksh, ks = t & ((1 << ksh) - 1);
    const int m16 = l & 15, q = l >> 4;
    __hip_bfloat16* dst = P + ((size_t)t*64 + l)*8;
    if (!pad) {
      const float* src = W + (size_t)(ks*32 + q*8)*256 + j*16 + m16;
      #pragma unroll
      for (int e = 0; e < 8; ++e)
        dst[e] = __float2bfloat16(src[(size_t)e*256]);
    } else {
      const int col = j*16 + m16;
      #pragma unroll
      for (int e = 0; e < 8; ++e)
        dst[e] = __float2bfloat16(col < 60 ?
                     W[(size_t)(ks*32 + q*8 + e)*60 + col] : 0.f);
    }
  } else if (bid < 360) {          // zero stats replicas: 96 blocks x 256 floats
    a.ws[(bid - 264) * 256 + tid] = 0.f;
  } else if (bid < 424) {          // x-embed: 16 rows per block
    int row0 = (bid - 360) * 16;
    #pragma unroll
    for (int r = 0; r < 16; ++r)
      a.xg[(size_t)(row0 + r)*256 + tid] =
          __float2bfloat16(xembed(a.centers, a.W_traj, a.b_traj, row0 + r, tid));
  } else {                         // zero incraw: 64 blocks x 4096 floats
    float* p = a.inc + (size_t)(bid - 424) * 4096;
    #pragma unroll
    for (int i = 0; i < 4; ++i)
      *reinterpret_cast<float4*>(p + (i*256 + tid)*4) = (float4){0.f,0.f,0.f,0.f};
  }
}

// ---- XR/XS = xg @ W1_{top,bot}: single-wave pure GEMM, grid 512 ----
__global__ __launch_bounds__(64) void k_xrs2(
    const __hip_bfloat16* __restrict__ xg,    // 1024 x 256
    const __hip_bfloat16* __restrict__ W1P,   // panel KC=16
    const float* __restrict__ b1,
    __hip_bfloat16* __restrict__ xrs) {       // XR ++ XS
  const int lane = threadIdx.x;
  const int m16 = lane & 15, quad = lane >> 4;
  const int ko = quad * 8;
  const int rt = blockIdx.x >> 3, s = blockIdx.x & 7;
  const int half = s >> 2, j0 = (s & 3) * 64;
  const int jg0 = (s & 3) * 4;
  const int row0 = rt * 16;
  __hip_bfloat16* dst = xrs + (size_t)half * 262144;

  f32x4 acc[4];
  #pragma unroll
  for (int jt = 0; jt < 4; ++jt) {
    float bv = half ? 0.f : b1[j0 + jt*16 + m16];
    acc[jt] = (f32x4){bv, bv, bv, bv};
  }
  #pragma unroll
  for (int ks = 0; ks < 8; ++ks) {
    short8 af = *reinterpret_cast<const short8*>(
        xg + (size_t)(row0 + m16)*256 + ks*32 + ko);
    short8 bf[4];
    #pragma unroll
    for (int jt = 0; jt < 4; ++jt)
      bf[jt] = *reinterpret_cast<const short8*>(
          W1P + (((size_t)(jg0 + jt)*16 + half*8 + ks)*64 + lane)*8);
    #pragma unroll
    for (int jt = 0; jt < 4; ++jt)
      acc[jt] = __builtin_amdgcn_mfma_f32_16x16x32_bf16(af, bf[jt], acc[jt], 0, 0, 0);
  }
  #pragma unroll
  for (int jt = 0; jt < 4; ++jt)
    #pragma unroll
    for (int r = 0; r < 4; ++r)
      dst[(size_t)(row0 + quad*4 + r)*256 + j0 + jt*16 + m16] =
          __float2bfloat16(acc[jt][r]);
}

// ===== edge MLP v144: 144-row tiles, 74.3KB LDS, 2 blocks/CU, shfl-fold stats ==
// Per 144-edge block, receivers n0..n0+3 with thresholds thr1 (1..63),
// thr2 = thr1+63 (always < 144), thr3 = thr1+126 (4th receiver iff < 144).
__global__ __launch_bounds__(256, 2) void k_mlp144(
    const __hip_bfloat16* __restrict__ xrs,   // XR ++ XS
    const __hip_bfloat16* __restrict__ W2P,   // panel KC=8
    const float* __restrict__ b2,
    __hip_bfloat16* __restrict__ outp,        // e2 sender-major
    float* __restrict__ stats,                // RSE x [512] replicas
    float* __restrict__ incraw) {             // 1024 x 256 f32 raw receiver sums
  __shared__ alignas(16) __hip_bfloat16 h1s[144][264];
  const int tid = threadIdx.x;
  const int w = tid >> 6, lane = tid & 63;
  const int m16 = lane & 15, quad = lane >> 4;
  const int ko = quad * 8;
  const int blk = blockIdx.x;                 // 448
  const int bb = blk / 28, lb = blk - bb*28;
  const int n0 = (lb * 144) / 63;
  const int thr1 = (n0 + 1) * 63 - lb * 144;  // 1..63
  const int thr2 = thr1 + 63;                 // always < 144
  const int thr3 = thr1 + 126;                // 4th receiver iff < 144
  const int colw = w * 64;

  // ---- h1 = elu(XR[rc] + XS[sd]) -> h1s; 16B vector loads, L2-hot ----
  {
    const int rg = tid >> 5;                  // 0..7
    const int c8 = (tid & 31) * 8;
    const __hip_bfloat16* xrb = xrs + (size_t)(bb*64 + n0)*256 + c8;
    const __hip_bfloat16* xsb = xrs + 262144 + (size_t)bb*64*256 + c8;
    union { uint4 u; __hip_bfloat16 h[8]; } vr0, vr1, vr2, vr3;
    vr0.u = *reinterpret_cast<const uint4*>(xrb);
    vr1.u = *reinterpret_cast<const uint4*>(xrb + 256);
    vr2.u = *reinterpret_cast<const uint4*>(xrb + 512);
    vr3.u = (thr3 < 144) ? *reinterpret_cast<const uint4*>(xrb + 768) : vr0.u;
    #pragma unroll
    for (int i = 0; i < 18; ++i) {
      int r = rg + i*8;
      int rc = n0 + ((r >= thr1) ? 1 : 0) + ((r >= thr2) ? 1 : 0)
                  + ((r >= thr3) ? 1 : 0);
      int jj = lb*144 + r - rc*63;
      int sd = jj + (jj >= rc ? 1 : 0);
      union { uint4 u; __hip_bfloat16 h[8]; } vs, va, o;
      vs.u = *reinterpret_cast<const uint4*>(xsb + (size_t)sd*256);
      va.u = (r >= thr3) ? vr3.u
           : (r >= thr2) ? vr2.u
           : (r >= thr1) ? vr1.u : vr0.u;
      #pragma unroll
      for (int j = 0; j < 8; ++j)
        o.h[j] = __float2bfloat16(eluf(__bfloat162float(va.h[j]) +
                                       __bfloat162float(vs.h[j])));
      *reinterpret_cast<uint4*>(&h1s[r][c8]) = o.u;
    }
  }
  __syncthreads();

  // ---- layer 2: 144x256 @ 256x256; B from coalesced panel ----
  f32x4 acc2[9][4];
  #pragma unroll
  for (int jt = 0; jt < 4; ++jt) {
    float bv = b2[colw + jt*16 + m16];
    #pragma unroll
    for (int mt = 0; mt < 9; ++mt) acc2[mt][jt] = (f32x4){bv, bv, bv, bv};
  }
  #pragma unroll
  for (int chunk = 0; chunk < 8; ++chunk) {
    const int k0 = chunk*32 + ko;
    short8 bf[4];
    #pragma unroll
    for (int jt = 0; jt < 4; ++jt)
      bf[jt] = *reinterpret_cast<const short8*>(
          W2P + (((size_t)(w*4 + jt)*8 + chunk)*64 + lane)*8);
    #pragma unroll
    for (int mt = 0; mt < 9; ++mt) {
      short8 af = *(const short8*)((const char*)h1s +
                      (size_t)(mt*16 + m16)*528 + k0*2);
      #pragma unroll
      for (int jt = 0; jt < 4; ++jt)
        acc2[mt][jt] = __builtin_amdgcn_mfma_f32_16x16x32_bf16(af, bf[jt],
                                                               acc2[mt][jt], 0, 0, 0);
    }
  }
  __syncthreads();   // all h1 reads done before h1s is overwritten with h2

  // ---- ELU(h2) -> h1s; quad-fold partials -> direct global atomics ----
  #pragma unroll
  for (int jt = 0; jt < 4; ++jt) {
    float s0 = 0.f, s1 = 0.f, s2 = 0.f, s3 = 0.f, sq = 0.f;
    #pragma unroll
    for (int mt = 0; mt < 9; ++mt)
      #pragma unroll
      for (int r = 0; r < 4; ++r) {
        int row = mt*16 + quad*4 + r;
        float hv = eluf(acc2[mt][jt][r]);
        h1s[row][colw + jt*16 + m16] = __float2bfloat16(hv);
        float g3 = (row >= thr3) ? hv : 0.f;
        float g2 = (row >= thr2) ? hv : 0.f;
        float g1 = (row >= thr1) ? hv : 0.f;
        s3 += g3; s2 += g2 - g3; s1 += g1 - g2; s0 += hv - g1;
        sq += hv * hv;
      }
    s0 += __shfl_xor(s0, 16); s0 += __shfl_xor(s0, 32);
    s1 += __shfl_xor(s1, 16); s1 += __shfl_xor(s1, 32);
    s2 += __shfl_xor(s2, 16); s2 += __shfl_xor(s2, 32);
    s3 += __shfl_xor(s3, 16); s3 += __shfl_xor(s3, 32);
    sq += __shfl_xor(sq, 16); sq += __shfl_xor(sq, 32);
    if (quad == 0) {
      int col = colw + jt*16 + m16;
      float* sb = stats + (size_t)(blk & (RSE - 1)) * 512;
      atomicAdd(&sb[col], s0 + s1 + s2 + s3);
      atomicAdd(&sb[256 + col], sq);
      atomicAdd(&incraw[(size_t)(bb*64 + n0)*256 + col], s0);
      atomicAdd(&incraw[(size_t)(bb*64 + n0 + 1)*256 + col], s1);
      atomicAdd(&incraw[(size_t)(bb*64 + n0 + 2)*256 + col], s2);
      if (thr3 < 144)
        atomicAdd(&incraw[(size_t)(bb*64 + n0 + 3)*256 + col], s3);
    }
  }
  __syncthreads();

  // sender-major writeout: row (rc,sd) -> e2[(bb*64+sd)*63 + jpos]
  #pragma unroll
  for (int i = 0; i < 18; ++i) {
    int u = i*256 + tid;
    int r = u >> 5, c = (u & 31) * 8;
    int rc = n0 + ((r >= thr1) ? 1 : 0) + ((r >= thr2) ? 1 : 0)
                + ((r >= thr3) ? 1 : 0);
    int jj = lb*144 + r - rc*63;
    int sd = jj + (jj >= rc ? 1 : 0);
    int jpos = rc - (jj < rc ? 1 : 0);
    *reinterpret_cast<uint4*>(outp + ((size_t)(bb*64 + sd)*63 + jpos)*HH + c) =
        *reinterpret_cast<const uint4*>(&h1s[r][c]);
  }
}

// ---- sender aggregation + replica fold + BN affine both halves: grid 1024x256 -
__global__ __launch_bounds__(256) void k_aggS(const __hip_bfloat16* __restrict__ e2,
                                              const float* __restrict__ incraw,
                                              const float* __restrict__ st,
                                              const float* __restrict__ gam,
                                              const float* __restrict__ bet,
                                              __hip_bfloat16* __restrict__ nodes) {
  __shared__ float red[8][256];
  const int bn = blockIdx.x;
  const int tid = threadIdx.x;
  const int c8 = (tid & 31) * 8;
  const int rg = tid >> 5;
  const __hip_bfloat16* base = e2 + (size_t)bn * 63 * HH;
  float s[8] = {0.f,0.f,0.f,0.f,0.f,0.f,0.f,0.f};
  for (int j = rg; j < 63; j += 8) {
    union { uint4 u; __hip_bfloat16 h[8]; } v;
    v.u = *reinterpret_cast<const uint4*>(base + (size_t)j*HH + c8);
    #pragma unroll
    for (int jj = 0; jj < 8; ++jj) s[jj] += __bfloat162float(v.h[jj]);
  }
  #pragma unroll
  for (int jj = 0; jj < 8; jj += 4)
    *reinterpret_cast<float4*>(&red[rg][c8 + jj]) =
        (float4){s[jj], s[jj+1], s[jj+2], s[jj+3]};
  // fold stats replicas while the LDS reduce settles (L2-hot)
  float ssum = 0.f, ssq = 0.f;
  #pragma unroll
  for (int r = 0; r < RSE; ++r) {
    ssum += st[(size_t)r*512 + tid];
    ssq  += st[(size_t)r*512 + 256 + tid];
  }
  __syncthreads();
  float S = 0.f;
  #pragma unroll
  for (int r = 0; r < 8; ++r) S += red[r][tid];
  const float inv = 1.f / (float)EROWS;
  float mean = ssum * inv;
  float var  = fmaxf(ssq * inv - mean*mean, 0.f);
  float a = gam[tid] * rsqrtf(var + 1e-5f);
  float c0 = bet[tid] - mean * a;
  float in_v  = a * (incraw[(size_t)bn*256 + tid] * (1.f/63.f)) + c0;
  float out_v = a * (S * (1.f/63.f)) + c0;
  nodes[(size_t)bn*512 + tid]       = __float2bfloat16(in_v);
  nodes[(size_t)bn*512 + 256 + tid] = __float2bfloat16(out_v);
}

// ================= node MLP layer 1: single-wave, grid 512 (32-col stripes) ====
__global__ __launch_bounds__(64) void k_n1(
    const __hip_bfloat16* __restrict__ nodes, // 1024 x 512
    const __hip_bfloat16* __restrict__ W1P,   // panel KC=16
    const float* __restrict__ b1,
    __hip_bfloat16* __restrict__ h1g) {       // 1024 x 256
  __shared__ alignas(16) __hip_bfloat16 hls[16][40];
  const int lane = threadIdx.x;
  const int m16 = lane & 15, quad = lane >> 4;
  const int ko = quad * 8;
  const int row0 = (blockIdx.x >> 3) * 16;
  const int jb = blockIdx.x & 7;
  const int j0 = jb * 32;

  f32x4 acc[2];
  #pragma unroll
  for (int jt = 0; jt < 2; ++jt) {
    float bv = b1[j0 + jt*16 + m16];
    acc[jt] = (f32x4){bv, bv, bv, bv};
  }
  #pragma unroll
  for (int ks = 0; ks < 16; ++ks) {
    short8 af = *reinterpret_cast<const short8*>(
        nodes + (size_t)(row0 + m16)*512 + ks*32 + ko);
    short8 bf[2];
    #pragma unroll
    for (int jt = 0; jt < 2; ++jt)
      bf[jt] = *reinterpret_cast<const short8*>(
          W1P + (((size_t)(jb*2 + jt)*16 + ks)*64 + lane)*8);
    #pragma unroll
    for (int jt = 0; jt < 2; ++jt)
      acc[jt] = __builtin_amdgcn_mfma_f32_16x16x32_bf16(af, bf[jt], acc[jt], 0, 0, 0);
  }
  #pragma unroll
  for (int jt = 0; jt < 2; ++jt)
    #pragma unroll
    for (int r = 0; r < 4; ++r)
      hls[quad*4 + r][jt*16 + m16] = __float2bfloat16(eluf(acc[jt][r]));
  {
    int r = lane >> 2, c = (lane & 3) * 8;
    *reinterpret_cast<uint4*>(h1g + (size_t)(row0 + r)*256 + j0 + c) =
        *reinterpret_cast<const uint4*>(&hls[r][c]);
  }
}

// ================= node MLP layer 2 + stats: single-wave, grid 512 =============
__global__ __launch_bounds__(64) void k_n2(
    const __hip_bfloat16* __restrict__ h1g,   // 1024 x 256
    const __hip_bfloat16* __restrict__ W2P,   // panel KC=8
    const float* __restrict__ b2,
    __hip_bfloat16* __restrict__ m2,          // 1024 x 256
    float* __restrict__ stats) {              // RSM x [512] replicas
  __shared__ alignas(16) __hip_bfloat16 hls[16][40];
  __shared__ float sst[2][32];
  const int lane = threadIdx.x;
  const int m16 = lane & 15, quad = lane >> 4;
  const int ko = quad * 8;
  const int row0 = (blockIdx.x >> 3) * 16;
  const int jb = blockIdx.x & 7;
  const int j0 = jb * 32;

  if (lane < 32) { sst[0][lane] = 0.f; sst[1][lane] = 0.f; }

  f32x4 acc[2];
  #pragma unroll
  for (int jt = 0; jt < 2; ++jt) {
    float bv = b2[j0 + jt*16 + m16];
    acc[jt] = (f32x4){bv, bv, bv, bv};
  }
  #pragma unroll
  for (int ks = 0; ks < 8; ++ks) {
    short8 af = *reinterpret_cast<const short8*>(
        h1g + (size_t)(row0 + m16)*256 + ks*32 + ko);
    short8 bf[2];
    #pragma unroll
    for (int jt = 0; jt < 2; ++jt)
      bf[jt] = *reinterpret_cast<const short8*>(
          W2P + (((size_t)(jb*2 + jt)*8 + ks)*64 + lane)*8);
    #pragma unroll
    for (int jt = 0; jt < 2; ++jt)
      acc[jt] = __builtin_amdgcn_mfma_f32_16x16x32_bf16(af, bf[jt], acc[jt], 0, 0, 0);
  }
  #pragma unroll
  for (int jt = 0; jt < 2; ++jt) {
    float ps = 0.f, pq = 0.f;
    #pragma unroll
    for (int r = 0; r < 4; ++r) {
      float hv = eluf(acc[jt][r]);
      hls[quad*4 + r][jt*16 + m16] = __float2bfloat16(hv);
      ps += hv; pq += hv * hv;
    }
    atomicAdd(&sst[0][jt*16 + m16], ps);
    atomicAdd(&sst[1][jt*16 + m16], pq);
  }
  if (lane < 32) {
    float* sb = stats + (size_t)(blockIdx.x & (RSM - 1)) * 512;  // replica
    atomicAdd(&sb[j0 + lane], sst[0][lane]);
    atomicAdd(&sb[256 + j0 + lane], sst[1][lane]);
  }
  {
    int r = lane >> 2, c = (lane & 3) * 8;
    *reinterpret_cast<uint4*>(m2 + (size_t)(row0 + r)*256 + j0 + c) =
        *reinterpret_cast<const uint4*>(&hls[r][c]);
  }
}

// ================= head fuse layer: single-wave, grid 512 ======================
__global__ __launch_bounds__(64) void k_hf(
    const __hip_bfloat16* __restrict__ xg,    // 1024 x 256
    const __hip_bfloat16* __restrict__ m2,    // 1024 x 256
    const float* __restrict__ stM,            // RSM x [512] replicas
    const float* __restrict__ gam,
    const float* __restrict__ bet,
    const __hip_bfloat16* __restrict__ WfP,   // panel KC=16
    const float* __restrict__ bfv,
    __hip_bfloat16* __restrict__ fg) {        // 1024 x 256
  __shared__ alignas(16) __hip_bfloat16 hls[16][40];
  __shared__ float bnA[256], bnC[256];
  const int lane = threadIdx.x;
  const int m16 = lane & 15, quad = lane >> 4;
  const int ko = quad * 8;
  const int row0 = (blockIdx.x >> 3) * 16;
  const int jb = blockIdx.x & 7;
  const int j0 = jb * 32;

  {
    const float inv = 1.f / (float)NROWS;
    #pragma unroll
    for (int j = 0; j < 4; ++j) {
      int k = lane*4 + j;
      float ssum = 0.f, ssq = 0.f;
      #pragma unroll
      for (int r = 0; r < RSM; ++r) {
        ssum += stM[(size_t)r*512 + k];
        ssq  += stM[(size_t)r*512 + 256 + k];
      }
      float mean = ssum * inv;
      float var  = fmaxf(ssq * inv - mean*mean, 0.f);
      float am = gam[k] * rsqrtf(var + 1e-5f);
      bnA[k] = am;
      bnC[k] = bet[k] - mean * am;
    }
  }

  f32x4 acc[2];
  #pragma unroll
  for (int jt = 0; jt < 2; ++jt) {
    float bv = bfv[j0 + jt*16 + m16];
    acc[jt] = (f32x4){bv, bv, bv, bv};
  }
  #pragma unroll
  for (int ks = 0; ks < 16; ++ks) {
    short8 af;
    if (ks < 8) {
      af = *reinterpret_cast<const short8*>(
          xg + (size_t)(row0 + m16)*256 + ks*32 + ko);
    } else {
      int k0 = (ks - 8)*32 + ko;
      union { uint4 u; __hip_bfloat16 h[8]; } v;
      v.u = *reinterpret_cast<const uint4*>(m2 + (size_t)(row0 + m16)*256 + k0);
      union { short8 s8; __hip_bfloat16 h[8]; } o;
      #pragma unroll
      for (int j = 0; j < 8; ++j)
        o.h[j] = __float2bfloat16(bnA[k0+j] * __bfloat162float(v.h[j]) + bnC[k0+j]);
      af = o.s8;
    }
    short8 bf[2];
    #pragma unroll
    for (int jt = 0; jt < 2; ++jt)
      bf[jt] = *reinterpret_cast<const short8*>(
          WfP + (((size_t)(jb*2 + jt)*16 + ks)*64 + lane)*8);
    #pragma unroll
    for (int jt = 0; jt < 2; ++jt)
      acc[jt] = __builtin_amdgcn_mfma_f32_16x16x32_bf16(af, bf[jt], acc[jt], 0, 0, 0);
  }
  #pragma unroll
  for (int jt = 0; jt < 2; ++jt)
    #pragma unroll
    for (int r = 0; r < 4; ++r)
      hls[quad*4 + r][jt*16 + m16] = __float2bfloat16(acc[jt][r]);   // no activation
  {
    int r = lane >> 2, c = (lane & 3) * 8;
    *reinterpret_cast<uint4*>(fg + (size_t)(row0 + r)*256 + j0 + c) =
        *reinterpret_cast<const uint4*>(&hls[r][c]);
  }
}

// ================= pred + cumsum: single-wave, grid 64 =========================
__global__ __launch_bounds__(64) void k_pred(
    const __hip_bfloat16* __restrict__ fg,    // 1024 x 256
    const __hip_bfloat16* __restrict__ WpP,   // panel KC=8 (zero-padded)
    const float* __restrict__ bp,
    const float* __restrict__ centers,
    float* __restrict__ out) {
  __shared__ float rl[16][68];
  const int lane = threadIdx.x;
  const int m16 = lane & 15, quad = lane >> 4;
  const int ko = quad * 8;
  const int row0 = blockIdx.x * 16;

  f32x4 acc[4];
  #pragma unroll
  for (int jt = 0; jt < 4; ++jt) {
    int c = jt*16 + m16;
    float bv = (c < 60) ? bp[c] : 0.f;
    acc[jt] = (f32x4){bv, bv, bv, bv};
  }
  #pragma unroll
  for (int ks = 0; ks < 8; ++ks) {
    short8 af = *reinterpret_cast<const short8*>(
        fg + (size_t)(row0 + m16)*256 + ks*32 + ko);
    short8 bf[4];
    #pragma unroll
    for (int jt = 0; jt < 4; ++jt)
      bf[jt] = *reinterpret_cast<const short8*>(
          WpP + (((size_t)jt*8 + ks)*64 + lane)*8);
    #pragma unroll
    for (int jt = 0; jt < 4; ++jt)
      acc[jt] = __builtin_amdgcn_mfma_f32_16x16x32_bf16(af, bf[jt], acc[jt], 0, 0, 0);
  }
  #pragma unroll
  for (int jt = 0; jt < 4; ++jt) {
    int c = jt*16 + m16;
    #pragma unroll
    for (int r = 0; r < 4; ++r) {
      int lr = quad*4 + r;
      rl[lr][c] = acc[jt][r];
      if (c < 60) out[(size_t)(row0 + lr)*60 + c] = acc[jt][r];
    }
  }
  if (lane < 32) {
    int lr = lane >> 1, xy = lane & 1;
    int grow = row0 + lr;
    float run = centers[(size_t)(grow*PREVN + 5)*2 + xy];
    #pragma unroll
    for (int p = 0; p < PREDN; ++p) {
      run += rl[lr][2*p + xy];
      out[61440 + (size_t)grow*60 + 2*p + xy] = run;
    }
  }
}

extern "C" void kernel_launch(void* const* d_in, const int* in_sizes, int n_in,
                              void* d_out, int out_size, void* d_ws, size_t ws_size,
                              hipStream_t stream) {
  const float* centers = (const float*)d_in[0];
  float* ws = (float*)d_ws;
  __hip_bfloat16* wb = (__hip_bfloat16*)(ws + F32_END);
  __hip_bfloat16* xrs = (__hip_bfloat16*)(ws + OFF_XRS);
  float* incraw = (float*)(wb + BO_H1G);   // overlays h1g+m2 (dead until k_n1)

  const float* W_traj = (const float*)d_in[3];
  const float* b_traj = (const float*)d_in[4];
  const float* n2e_b1 = (const float*)d_in[6];
  const float* n2e_b2 = (const float*)d_in[8];
  const float* n2e_g  = (const float*)d_in[9];
  const float* n2e_be = (const float*)d_in[10];
  const float* e2n_b1 = (const float*)d_in[12];
  const float* e2n_b2 = (const float*)d_in[14];
  const float* e2n_g  = (const float*)d_in[15];
  const float* e2n_be = (const float*)d_in[16];
  const float* b_fuse = (const float*)d_in[18];
  const float* b_pred = (const float*)d_in[20];

  PrepArgs pa;
  pa.centers = centers; pa.W_traj = W_traj; pa.b_traj = b_traj;
  pa.n2e_W1 = (const float*)d_in[5];  pa.n2e_W2 = (const float*)d_in[7];
  pa.e2n_W1 = (const float*)d_in[11]; pa.e2n_W2 = (const float*)d_in[13];
  pa.W_fuse = (const float*)d_in[17]; pa.W_pred = (const float*)d_in[19];
  pa.ws = ws; pa.inc = incraw;
  pa.p1e = wb + BO_W1TE; pa.p2e = wb + BO_W2TE;
  pa.p1n = wb + BO_W1TN; pa.p2n = wb + BO_W2TN;
  pa.pf = wb + BO_WFT;   pa.pp = wb + BO_WPT;
  pa.xg = wb + BO_XG;

  k_prep<<<488, 256, 0, stream>>>(pa);
  k_xrs2<<<512, 64, 0, stream>>>(wb + BO_XG, wb + BO_W1TE, n2e_b1, xrs);
  k_mlp144<<<EROWS/144, 256, 0, stream>>>(xrs, wb + BO_W2TE, n2e_b2, wb + BO_E2,
                                          ws + OFF_STATS_E, incraw);
  k_aggS<<<NROWS, 256, 0, stream>>>(wb + BO_E2, incraw, ws + OFF_STATS_E,
                                    n2e_g, n2e_be, wb + BO_NODES);
  k_n1<<<512, 64, 0, stream>>>(wb + BO_NODES, wb + BO_W1TN, e2n_b1, wb + BO_H1G);
  k_n2<<<512, 64, 0, stream>>>(wb + BO_H1G, wb + BO_W2TN, e2n_b2, wb + BO_M2,
                               ws + OFF_STATS_M);
  k_hf<<<512, 64, 0, stream>>>(wb + BO_XG, wb + BO_M2, ws + OFF_STATS_M,
                               e2n_g, e2n_be, wb + BO_WFT, b_fuse, wb + BO_FG);
  k_pred<<<64, 64, 0, stream>>>(wb + BO_FG, wb + BO_WPT, b_pred, centers,
                                (float*)d_out);
}

// Round 10
// 172.931 us; speedup vs baseline: 1.0783x; 1.0783x over previous
//
#include <hip/hip_runtime.h>
#include <hip/hip_bf16.h>

#define BB 16
#define NN 64
#define PREVN 6
#define PREDN 30
#define HH 256
#define EE 4032              // NN*(NN-1)
#define EROWS (BB*EE)        // 64512
#define NROWS (BB*NN)        // 1024
#define RSE 32               // edge-stats replicas
#define RSM 16               // node-stats replicas

typedef short short8 __attribute__((ext_vector_type(8)));
typedef float f32x4 __attribute__((ext_vector_type(4)));

// ---- f32 workspace layout (float element offsets) ----
enum : int {
  OFF_STATS_E = 0,       // RSE replicas x [512]: [0:256]=sum [256:512]=sumsq
  OFF_STATS_M = 16384,   // RSM replicas x [512]
  OFF_XRS     = 32768,   // 262144 f32 slots = 524288 bf16: XR ++ XS
  F32_END     = 294912
};
// ---- bf16 area (element offsets within wb = (bf16*)(ws + F32_END)) ----
// Weight panels in MFMA-fragment order:
//   P[((j*KC + ks)*64 + lane)*8 + e] = W[ks*32 + (lane>>4)*8 + e][j*16 + (lane&15)]
enum : size_t {
  BO_W1TE  = 0,          // 256*512 (n2e W1 panel, KC=16)
  BO_W2TE  = 131072,     // 256*256 (n2e W2 panel, KC=8)
  BO_W1TN  = 196608,     // 256*512 (e2n W1 panel, KC=16)
  BO_W2TN  = 327680,     // 256*256 (e2n W2 panel, KC=8)
  BO_WFT   = 393216,     // 256*512 (W_fuse panel, KC=16)
  BO_WPT   = 524288,     // 64*256  (W_pred panel, KC=8, cols 60..63 zero)
  BO_XG    = 540672,     // 1024*256 raw x (bf16)
  BO_NODES = 802816,     // 1024*512
  BO_H1G   = 1327104,    // 1024*256 node-MLP h1  (overlaid by incraw pre-k_n1)
  BO_M2    = 1589248,    // 1024*256
  BO_FG    = 1851392,    // 1024*256 fused
  BO_E2    = 2113536     // 64512*256 SENDER-major: row = (b*64+send)*63 + jpos
};
// incraw = (float*)(wb + BO_H1G): 1024x256 f32 (1 MB), dead before k_n1 runs.

// fast ELU: exp(x)-1 via v_exp_f32
__device__ __forceinline__ float eluf(float v) { return v > 0.f ? v : __expf(v) - 1.f; }

// compute one x-embed element: row rr (global), col
__device__ __forceinline__ float xembed(const float* __restrict__ centers,
                                        const float* __restrict__ Wt,
                                        const float* __restrict__ bt,
                                        int rr, int col) {
  const float* c = centers + rr * 12;
  float acc = bt[col];
  #pragma unroll
  for (int t = 0; t < 5; ++t) {
    float dx = c[(t+1)*2 + 0] - c[t*2 + 0];
    float dy = c[(t+1)*2 + 1] - c[t*2 + 1];
    acc += dx * Wt[(2 + 2*t)*HH + col] + dy * Wt[(3 + 2*t)*HH + col];
  }
  return acc;
}

// ================= prep: weight panels + zero stats/incraw + x-embed ===========
struct PrepArgs {
  const float *centers, *W_traj, *b_traj;
  const float *n2e_W1, *n2e_W2, *e2n_W1, *e2n_W2, *W_fuse, *W_pred;
  float* ws;
  float* inc;                      // incraw 1024x256 f32
  __hip_bfloat16 *p1e, *p2e, *p1n, *p2n, *pf, *pp, *xg;
};

__global__ __launch_bounds__(256) void k_prep(PrepArgs a) {
  const int bid = blockIdx.x, tid = threadIdx.x;
  if (bid < 264) {                 // weight panels, 4 tiles (1KB each) per block
    const float* W; __hip_bfloat16* P; int ksh, t0, pad = 0;
    if (bid < 64)       { W = a.n2e_W1; P = a.p1e; ksh = 4; t0 = bid*4; }
    else if (bid < 96)  { W = a.n2e_W2; P = a.p2e; ksh = 3; t0 = (bid-64)*4; }
    else if (bid < 160) { W = a.e2n_W1; P = a.p1n; ksh = 4; t0 = (bid-96)*4; }
    else if (bid < 192) { W = a.e2n_W2; P = a.p2n; ksh = 3; t0 = (bid-160)*4; }
    else if (bid < 256) { W = a.W_fuse; P = a.pf;  ksh = 4; t0 = (bid-192)*4; }
    else                { W = a.W_pred; P = a.pp;  ksh = 3; t0 = (bid-256)*4; pad = 1; }
    const int l = tid & 63, sub = tid >> 6;
    const int t = t0 + sub;
    const int j = t >> ksh, ks = t & ((1 << ksh) - 1);
    const int m16 = l & 15, q = l >> 4;
    __hip_bfloat16* dst = P + ((size_t)t*64 + l)*8;
    if (!pad) {
      const float* src = W + (size_t)(ks*32 + q*8)*256 + j*16 + m16;
      #pragma unroll
      for (int e = 0; e < 8; ++e)
        dst[e] = __float2bfloat16(src[(size_t)e*256]);
    } else {
      const int col = j*16 + m16;
      #pragma unroll
      for (int e = 0; e < 8; ++e)
        dst[e] = __float2bfloat16(col < 60 ?
                     W[(size_t)(ks*32 + q*8 + e)*60 + col] : 0.f);
    }
  } else if (bid < 360) {          // zero stats replicas: 96 blocks x 256 floats
    a.ws[(bid - 264) * 256 + tid] = 0.f;
  } else if (bid < 424) {          // x-embed: 16 rows per block
    int row0 = (bid - 360) * 16;
    #pragma unroll
    for (int r = 0; r < 16; ++r)
      a.xg[(size_t)(row0 + r)*256 + tid] =
          __float2bfloat16(xembed(a.centers, a.W_traj, a.b_traj, row0 + r, tid));
  } else {                         // zero incraw: 64 blocks x 4096 floats
    float* p = a.inc + (size_t)(bid - 424) * 4096;
    #pragma unroll
    for (int i = 0; i < 4; ++i)
      *reinterpret_cast<float4*>(p + (i*256 + tid)*4) = (float4){0.f,0.f,0.f,0.f};
  }
}

// ---- XR/XS = xg @ W1_{top,bot}: single-wave pure GEMM, grid 512 ----
__global__ __launch_bounds__(64) void k_xrs2(
    const __hip_bfloat16* __restrict__ xg,    // 1024 x 256
    const __hip_bfloat16* __restrict__ W1P,   // panel KC=16
    const float* __restrict__ b1,
    __hip_bfloat16* __restrict__ xrs) {       // XR ++ XS
  const int lane = threadIdx.x;
  const int m16 = lane & 15, quad = lane >> 4;
  const int ko = quad * 8;
  const int rt = blockIdx.x >> 3, s = blockIdx.x & 7;
  const int half = s >> 2, j0 = (s & 3) * 64;
  const int jg0 = (s & 3) * 4;
  const int row0 = rt * 16;
  __hip_bfloat16* dst = xrs + (size_t)half * 262144;

  f32x4 acc[4];
  #pragma unroll
  for (int jt = 0; jt < 4; ++jt) {
    float bv = half ? 0.f : b1[j0 + jt*16 + m16];
    acc[jt] = (f32x4){bv, bv, bv, bv};
  }
  #pragma unroll
  for (int ks = 0; ks < 8; ++ks) {
    short8 af = *reinterpret_cast<const short8*>(
        xg + (size_t)(row0 + m16)*256 + ks*32 + ko);
    short8 bf[4];
    #pragma unroll
    for (int jt = 0; jt < 4; ++jt)
      bf[jt] = *reinterpret_cast<const short8*>(
          W1P + (((size_t)(jg0 + jt)*16 + half*8 + ks)*64 + lane)*8);
    #pragma unroll
    for (int jt = 0; jt < 4; ++jt)
      acc[jt] = __builtin_amdgcn_mfma_f32_16x16x32_bf16(af, bf[jt], acc[jt], 0, 0, 0);
  }
  #pragma unroll
  for (int jt = 0; jt < 4; ++jt)
    #pragma unroll
    for (int r = 0; r < 4; ++r)
      dst[(size_t)(row0 + quad*4 + r)*256 + j0 + jt*16 + m16] =
          __float2bfloat16(acc[jt][r]);
}

// ===== edge MLP v96: 96-row tiles, 50.7KB LDS, 3 blocks/CU, shfl-fold stats ====
// Per 96-edge block, receivers n0 (r<thr1), n0+1 (thr1<=r<thr2), n0+2 (r>=thr2)
// with thr1 = 63*(n0+1) - 96*lb, thr2 = thr1 + 63 (n0+2 exists iff thr2 < 96).
// No sst LDS: column partials fold across quads via shfl_xor(16/32), quad-0
// lanes issue the global atomics directly.
__global__ __launch_bounds__(256, 3) void k_mlp96(
    const __hip_bfloat16* __restrict__ xrs,   // XR ++ XS
    const __hip_bfloat16* __restrict__ W2P,   // panel KC=8
    const float* __restrict__ b2,
    __hip_bfloat16* __restrict__ outp,        // e2 sender-major
    float* __restrict__ stats,                // RSE x [512] replicas
    float* __restrict__ incraw) {             // 1024 x 256 f32 raw receiver sums
  __shared__ alignas(16) __hip_bfloat16 h1s[96][264];
  const int tid = threadIdx.x;
  const int w = tid >> 6, lane = tid & 63;
  const int m16 = lane & 15, quad = lane >> 4;
  const int ko = quad * 8;
  const int blk = blockIdx.x;                 // 672
  const int bb = blk / 42, lb = blk - bb*42;
  const int n0 = (lb * 96) / 63;
  const int thr1 = (n0 + 1) * 63 - lb * 96;   // 1..63
  const int thr2 = thr1 + 63;                 // may be >= 96 (no 3rd receiver)
  const int colw = w * 64;

  // ---- h1 = elu(XR[rc] + XS[sd]) -> h1s; 16B vector loads, L2-hot ----
  {
    const int rg = tid >> 5;                  // 0..7
    const int c8 = (tid & 31) * 8;
    const __hip_bfloat16* xrb = xrs + (size_t)(bb*64 + n0)*256 + c8;
    const __hip_bfloat16* xsb = xrs + 262144 + (size_t)bb*64*256 + c8;
    union { uint4 u; __hip_bfloat16 h[8]; } vr0, vr1, vr2;
    vr0.u = *reinterpret_cast<const uint4*>(xrb);
    vr1.u = *reinterpret_cast<const uint4*>(xrb + 256);
    vr2.u = (thr2 < 96) ? *reinterpret_cast<const uint4*>(xrb + 512) : vr0.u;
    #pragma unroll
    for (int i = 0; i < 12; ++i) {
      int r = rg + i*8;
      int rc = n0 + ((r >= thr1) ? 1 : 0) + ((r >= thr2) ? 1 : 0);
      int jj = lb*96 + r - rc*63;
      int sd = jj + (jj >= rc ? 1 : 0);
      union { uint4 u; __hip_bfloat16 h[8]; } vs, va, o;
      vs.u = *reinterpret_cast<const uint4*>(xsb + (size_t)sd*256);
      va.u = (r >= thr2) ? vr2.u : ((r >= thr1) ? vr1.u : vr0.u);
      #pragma unroll
      for (int j = 0; j < 8; ++j)
        o.h[j] = __float2bfloat16(eluf(__bfloat162float(va.h[j]) +
                                       __bfloat162float(vs.h[j])));
      *reinterpret_cast<uint4*>(&h1s[r][c8]) = o.u;
    }
  }
  __syncthreads();

  // ---- layer 2: 96x256 @ 256x256; B from coalesced panel ----
  f32x4 acc2[6][4];
  #pragma unroll
  for (int jt = 0; jt < 4; ++jt) {
    float bv = b2[colw + jt*16 + m16];
    #pragma unroll
    for (int mt = 0; mt < 6; ++mt) acc2[mt][jt] = (f32x4){bv, bv, bv, bv};
  }
  #pragma unroll
  for (int chunk = 0; chunk < 8; ++chunk) {
    const int k0 = chunk*32 + ko;
    short8 af[6], bf[4];
    #pragma unroll
    for (int jt = 0; jt < 4; ++jt)
      bf[jt] = *reinterpret_cast<const short8*>(
          W2P + (((size_t)(w*4 + jt)*8 + chunk)*64 + lane)*8);
    #pragma unroll
    for (int mt = 0; mt < 6; ++mt)
      af[mt] = *(const short8*)((const char*)h1s +
                   (size_t)(mt*16 + m16)*528 + k0*2);
    #pragma unroll
    for (int mt = 0; mt < 6; ++mt)
      #pragma unroll
      for (int jt = 0; jt < 4; ++jt)
        acc2[mt][jt] = __builtin_amdgcn_mfma_f32_16x16x32_bf16(af[mt], bf[jt],
                                                               acc2[mt][jt], 0, 0, 0);
  }
  __syncthreads();   // all h1 reads done before h1s is overwritten with h2

  // ---- ELU(h2) -> h1s; quad-fold partials -> direct global atomics ----
  #pragma unroll
  for (int jt = 0; jt < 4; ++jt) {
    float s0 = 0.f, s1 = 0.f, s2 = 0.f, sq = 0.f;
    #pragma unroll
    for (int mt = 0; mt < 6; ++mt)
      #pragma unroll
      for (int r = 0; r < 4; ++r) {
        int row = mt*16 + quad*4 + r;
        float hv = eluf(acc2[mt][jt][r]);
        h1s[row][colw + jt*16 + m16] = __float2bfloat16(hv);
        float v2 = (row >= thr2) ? hv : 0.f;
        float v1 = (row >= thr1) ? hv - v2 : 0.f;
        s2 += v2; s1 += v1; s0 += hv - v1 - v2;
        sq += hv * hv;
      }
    s0 += __shfl_xor(s0, 16); s0 += __shfl_xor(s0, 32);
    s1 += __shfl_xor(s1, 16); s1 += __shfl_xor(s1, 32);
    s2 += __shfl_xor(s2, 16); s2 += __shfl_xor(s2, 32);
    sq += __shfl_xor(sq, 16); sq += __shfl_xor(sq, 32);
    if (quad == 0) {
      int col = colw + jt*16 + m16;
      float* sb = stats + (size_t)(blk & (RSE - 1)) * 512;
      atomicAdd(&sb[col], s0 + s1 + s2);
      atomicAdd(&sb[256 + col], sq);
      atomicAdd(&incraw[(size_t)(bb*64 + n0)*256 + col], s0);
      atomicAdd(&incraw[(size_t)(bb*64 + n0 + 1)*256 + col], s1);
      if (thr2 < 96)
        atomicAdd(&incraw[(size_t)(bb*64 + n0 + 2)*256 + col], s2);
    }
  }
  __syncthreads();

  // sender-major writeout: row (rc,sd) -> e2[(bb*64+sd)*63 + jpos]
  #pragma unroll
  for (int i = 0; i < 12; ++i) {
    int u = i*256 + tid;
    int r = u >> 5, c = (u & 31) * 8;
    int rc = n0 + ((r >= thr1) ? 1 : 0) + ((r >= thr2) ? 1 : 0);
    int jj = lb*96 + r - rc*63;
    int sd = jj + (jj >= rc ? 1 : 0);
    int jpos = rc - (jj < rc ? 1 : 0);
    *reinterpret_cast<uint4*>(outp + ((size_t)(bb*64 + sd)*63 + jpos)*HH + c) =
        *reinterpret_cast<const uint4*>(&h1s[r][c]);
  }
}

// ---- sender aggregation + replica fold + BN affine both halves: grid 1024x256 -
__global__ __launch_bounds__(256) void k_aggS(const __hip_bfloat16* __restrict__ e2,
                                              const float* __restrict__ incraw,
                                              const float* __restrict__ st,
                                              const float* __restrict__ gam,
                                              const float* __restrict__ bet,
                                              __hip_bfloat16* __restrict__ nodes) {
  __shared__ float red[8][256];
  const int bn = blockIdx.x;
  const int tid = threadIdx.x;
  const int c8 = (tid & 31) * 8;
  const int rg = tid >> 5;
  const __hip_bfloat16* base = e2 + (size_t)bn * 63 * HH;
  float s[8] = {0.f,0.f,0.f,0.f,0.f,0.f,0.f,0.f};
  for (int j = rg; j < 63; j += 8) {
    union { uint4 u; __hip_bfloat16 h[8]; } v;
    v.u = *reinterpret_cast<const uint4*>(base + (size_t)j*HH + c8);
    #pragma unroll
    for (int jj = 0; jj < 8; ++jj) s[jj] += __bfloat162float(v.h[jj]);
  }
  #pragma unroll
  for (int jj = 0; jj < 8; jj += 4)
    *reinterpret_cast<float4*>(&red[rg][c8 + jj]) =
        (float4){s[jj], s[jj+1], s[jj+2], s[jj+3]};
  // fold stats replicas while the LDS reduce settles (L2-hot)
  float ssum = 0.f, ssq = 0.f;
  #pragma unroll
  for (int r = 0; r < RSE; ++r) {
    ssum += st[(size_t)r*512 + tid];
    ssq  += st[(size_t)r*512 + 256 + tid];
  }
  __syncthreads();
  float S = 0.f;
  #pragma unroll
  for (int r = 0; r < 8; ++r) S += red[r][tid];
  const float inv = 1.f / (float)EROWS;
  float mean = ssum * inv;
  float var  = fmaxf(ssq * inv - mean*mean, 0.f);
  float a = gam[tid] * rsqrtf(var + 1e-5f);
  float c0 = bet[tid] - mean * a;
  float in_v  = a * (incraw[(size_t)bn*256 + tid] * (1.f/63.f)) + c0;
  float out_v = a * (S * (1.f/63.f)) + c0;
  nodes[(size_t)bn*512 + tid]       = __float2bfloat16(in_v);
  nodes[(size_t)bn*512 + 256 + tid] = __float2bfloat16(out_v);
}

// ================= node MLP layer 1: single-wave, grid 512 (32-col stripes) ====
__global__ __launch_bounds__(64) void k_n1(
    const __hip_bfloat16* __restrict__ nodes, // 1024 x 512
    const __hip_bfloat16* __restrict__ W1P,   // panel KC=16
    const float* __restrict__ b1,
    __hip_bfloat16* __restrict__ h1g) {       // 1024 x 256
  __shared__ alignas(16) __hip_bfloat16 hls[16][40];
  const int lane = threadIdx.x;
  const int m16 = lane & 15, quad = lane >> 4;
  const int ko = quad * 8;
  const int row0 = (blockIdx.x >> 3) * 16;
  const int jb = blockIdx.x & 7;
  const int j0 = jb * 32;

  f32x4 acc[2];
  #pragma unroll
  for (int jt = 0; jt < 2; ++jt) {
    float bv = b1[j0 + jt*16 + m16];
    acc[jt] = (f32x4){bv, bv, bv, bv};
  }
  #pragma unroll
  for (int ks = 0; ks < 16; ++ks) {
    short8 af = *reinterpret_cast<const short8*>(
        nodes + (size_t)(row0 + m16)*512 + ks*32 + ko);
    short8 bf[2];
    #pragma unroll
    for (int jt = 0; jt < 2; ++jt)
      bf[jt] = *reinterpret_cast<const short8*>(
          W1P + (((size_t)(jb*2 + jt)*16 + ks)*64 + lane)*8);
    #pragma unroll
    for (int jt = 0; jt < 2; ++jt)
      acc[jt] = __builtin_amdgcn_mfma_f32_16x16x32_bf16(af, bf[jt], acc[jt], 0, 0, 0);
  }
  #pragma unroll
  for (int jt = 0; jt < 2; ++jt)
    #pragma unroll
    for (int r = 0; r < 4; ++r)
      hls[quad*4 + r][jt*16 + m16] = __float2bfloat16(eluf(acc[jt][r]));
  {
    int r = lane >> 2, c = (lane & 3) * 8;
    *reinterpret_cast<uint4*>(h1g + (size_t)(row0 + r)*256 + j0 + c) =
        *reinterpret_cast<const uint4*>(&hls[r][c]);
  }
}

// ================= node MLP layer 2 + stats: single-wave, grid 512 =============
__global__ __launch_bounds__(64) void k_n2(
    const __hip_bfloat16* __restrict__ h1g,   // 1024 x 256
    const __hip_bfloat16* __restrict__ W2P,   // panel KC=8
    const float* __restrict__ b2,
    __hip_bfloat16* __restrict__ m2,          // 1024 x 256
    float* __restrict__ stats) {              // RSM x [512] replicas
  __shared__ alignas(16) __hip_bfloat16 hls[16][40];
  __shared__ float sst[2][32];
  const int lane = threadIdx.x;
  const int m16 = lane & 15, quad = lane >> 4;
  const int ko = quad * 8;
  const int row0 = (blockIdx.x >> 3) * 16;
  const int jb = blockIdx.x & 7;
  const int j0 = jb * 32;

  if (lane < 32) { sst[0][lane] = 0.f; sst[1][lane] = 0.f; }

  f32x4 acc[2];
  #pragma unroll
  for (int jt = 0; jt < 2; ++jt) {
    float bv = b2[j0 + jt*16 + m16];
    acc[jt] = (f32x4){bv, bv, bv, bv};
  }
  #pragma unroll
  for (int ks = 0; ks < 8; ++ks) {
    short8 af = *reinterpret_cast<const short8*>(
        h1g + (size_t)(row0 + m16)*256 + ks*32 + ko);
    short8 bf[2];
    #pragma unroll
    for (int jt = 0; jt < 2; ++jt)
      bf[jt] = *reinterpret_cast<const short8*>(
          W2P + (((size_t)(jb*2 + jt)*8 + ks)*64 + lane)*8);
    #pragma unroll
    for (int jt = 0; jt < 2; ++jt)
      acc[jt] = __builtin_amdgcn_mfma_f32_16x16x32_bf16(af, bf[jt], acc[jt], 0, 0, 0);
  }
  #pragma unroll
  for (int jt = 0; jt < 2; ++jt) {
    float ps = 0.f, pq = 0.f;
    #pragma unroll
    for (int r = 0; r < 4; ++r) {
      float hv = eluf(acc[jt][r]);
      hls[quad*4 + r][jt*16 + m16] = __float2bfloat16(hv);
      ps += hv; pq += hv * hv;
    }
    atomicAdd(&sst[0][jt*16 + m16], ps);
    atomicAdd(&sst[1][jt*16 + m16], pq);
  }
  if (lane < 32) {
    float* sb = stats + (size_t)(blockIdx.x & (RSM - 1)) * 512;  // replica
    atomicAdd(&sb[j0 + lane], sst[0][lane]);
    atomicAdd(&sb[256 + j0 + lane], sst[1][lane]);
  }
  {
    int r = lane >> 2, c = (lane & 3) * 8;
    *reinterpret_cast<uint4*>(m2 + (size_t)(row0 + r)*256 + j0 + c) =
        *reinterpret_cast<const uint4*>(&hls[r][c]);
  }
}

// ================= head fuse layer: single-wave, grid 512 ======================
__global__ __launch_bounds__(64) void k_hf(
    const __hip_bfloat16* __restrict__ xg,    // 1024 x 256
    const __hip_bfloat16* __restrict__ m2,    // 1024 x 256
    const float* __restrict__ stM,            // RSM x [512] replicas
    const float* __restrict__ gam,
    const float* __restrict__ bet,
    const __hip_bfloat16* __restrict__ WfP,   // panel KC=16
    const float* __restrict__ bfv,
    __hip_bfloat16* __restrict__ fg) {        // 1024 x 256
  __shared__ alignas(16) __hip_bfloat16 hls[16][40];
  __shared__ float bnA[256], bnC[256];
  const int lane = threadIdx.x;
  const int m16 = lane & 15, quad = lane >> 4;
  const int ko = quad * 8;
  const int row0 = (blockIdx.x >> 3) * 16;
  const int jb = blockIdx.x & 7;
  const int j0 = jb * 32;

  {
    const float inv = 1.f / (float)NROWS;
    #pragma unroll
    for (int j = 0; j < 4; ++j) {
      int k = lane*4 + j;
      float ssum = 0.f, ssq = 0.f;
      #pragma unroll
      for (int r = 0; r < RSM; ++r) {
        ssum += stM[(size_t)r*512 + k];
        ssq  += stM[(size_t)r*512 + 256 + k];
      }
      float mean = ssum * inv;
      float var  = fmaxf(ssq * inv - mean*mean, 0.f);
      float am = gam[k] * rsqrtf(var + 1e-5f);
      bnA[k] = am;
      bnC[k] = bet[k] - mean * am;
    }
  }

  f32x4 acc[2];
  #pragma unroll
  for (int jt = 0; jt < 2; ++jt) {
    float bv = bfv[j0 + jt*16 + m16];
    acc[jt] = (f32x4){bv, bv, bv, bv};
  }
  #pragma unroll
  for (int ks = 0; ks < 16; ++ks) {
    short8 af;
    if (ks < 8) {
      af = *reinterpret_cast<const short8*>(
          xg + (size_t)(row0 + m16)*256 + ks*32 + ko);
    } else {
      int k0 = (ks - 8)*32 + ko;
      union { uint4 u; __hip_bfloat16 h[8]; } v;
      v.u = *reinterpret_cast<const uint4*>(m2 + (size_t)(row0 + m16)*256 + k0);
      union { short8 s8; __hip_bfloat16 h[8]; } o;
      #pragma unroll
      for (int j = 0; j < 8; ++j)
        o.h[j] = __float2bfloat16(bnA[k0+j] * __bfloat162float(v.h[j]) + bnC[k0+j]);
      af = o.s8;
    }
    short8 bf[2];
    #pragma unroll
    for (int jt = 0; jt < 2; ++jt)
      bf[jt] = *reinterpret_cast<const short8*>(
          WfP + (((size_t)(jb*2 + jt)*16 + ks)*64 + lane)*8);
    #pragma unroll
    for (int jt = 0; jt < 2; ++jt)
      acc[jt] = __builtin_amdgcn_mfma_f32_16x16x32_bf16(af, bf[jt], acc[jt], 0, 0, 0);
  }
  #pragma unroll
  for (int jt = 0; jt < 2; ++jt)
    #pragma unroll
    for (int r = 0; r < 4; ++r)
      hls[quad*4 + r][jt*16 + m16] = __float2bfloat16(acc[jt][r]);   // no activation
  {
    int r = lane >> 2, c = (lane & 3) * 8;
    *reinterpret_cast<uint4*>(fg + (size_t)(row0 + r)*256 + j0 + c) =
        *reinterpret_cast<const uint4*>(&hls[r][c]);
  }
}

// ================= pred + cumsum: single-wave, grid 64 =========================
__global__ __launch_bounds__(64) void k_pred(
    const __hip_bfloat16* __restrict__ fg,    // 1024 x 256
    const __hip_bfloat16* __restrict__ WpP,   // panel KC=8 (zero-padded)
    const float* __restrict__ bp,
    const float* __restrict__ centers,
    float* __restrict__ out) {
  __shared__ float rl[16][68];
  const int lane = threadIdx.x;
  const int m16 = lane & 15, quad = lane >> 4;
  const int ko = quad * 8;
  const int row0 = blockIdx.x * 16;

  f32x4 acc[4];
  #pragma unroll
  for (int jt = 0; jt < 4; ++jt) {
    int c = jt*16 + m16;
    float bv = (c < 60) ? bp[c] : 0.f;
    acc[jt] = (f32x4){bv, bv, bv, bv};
  }
  #pragma unroll
  for (int ks = 0; ks < 8; ++ks) {
    short8 af = *reinterpret_cast<const short8*>(
        fg + (size_t)(row0 + m16)*256 + ks*32 + ko);
    short8 bf[4];
    #pragma unroll
    for (int jt = 0; jt < 4; ++jt)
      bf[jt] = *reinterpret_cast<const short8*>(
          WpP + (((size_t)jt*8 + ks)*64 + lane)*8);
    #pragma unroll
    for (int jt = 0; jt < 4; ++jt)
      acc[jt] = __builtin_amdgcn_mfma_f32_16x16x32_bf16(af, bf[jt], acc[jt], 0, 0, 0);
  }
  #pragma unroll
  for (int jt = 0; jt < 4; ++jt) {
    int c = jt*16 + m16;
    #pragma unroll
    for (int r = 0; r < 4; ++r) {
      int lr = quad*4 + r;
      rl[lr][c] = acc[jt][r];
      if (c < 60) out[(size_t)(row0 + lr)*60 + c] = acc[jt][r];
    }
  }
  if (lane < 32) {
    int lr = lane >> 1, xy = lane & 1;
    int grow = row0 + lr;
    float run = centers[(size_t)(grow*PREVN + 5)*2 + xy];
    #pragma unroll
    for (int p = 0; p < PREDN; ++p) {
      run += rl[lr][2*p + xy];
      out[61440 + (size_t)grow*60 + 2*p + xy] = run;
    }
  }
}

extern "C" void kernel_launch(void* const* d_in, const int* in_sizes, int n_in,
                              void* d_out, int out_size, void* d_ws, size_t ws_size,
                              hipStream_t stream) {
  const float* centers = (const float*)d_in[0];
  float* ws = (float*)d_ws;
  __hip_bfloat16* wb = (__hip_bfloat16*)(ws + F32_END);
  __hip_bfloat16* xrs = (__hip_bfloat16*)(ws + OFF_XRS);
  float* incraw = (float*)(wb + BO_H1G);   // overlays h1g+m2 (dead until k_n1)

  const float* W_traj = (const float*)d_in[3];
  const float* b_traj = (const float*)d_in[4];
  const float* n2e_b1 = (const float*)d_in[6];
  const float* n2e_b2 = (const float*)d_in[8];
  const float* n2e_g  = (const float*)d_in[9];
  const float* n2e_be = (const float*)d_in[10];
  const float* e2n_b1 = (const float*)d_in[12];
  const float* e2n_b2 = (const float*)d_in[14];
  const float* e2n_g  = (const float*)d_in[15];
  const float* e2n_be = (const float*)d_in[16];
  const float* b_fuse = (const float*)d_in[18];
  const float* b_pred = (const float*)d_in[20];

  PrepArgs pa;
  pa.centers = centers; pa.W_traj = W_traj; pa.b_traj = b_traj;
  pa.n2e_W1 = (const float*)d_in[5];  pa.n2e_W2 = (const float*)d_in[7];
  pa.e2n_W1 = (const float*)d_in[11]; pa.e2n_W2 = (const float*)d_in[13];
  pa.W_fuse = (const float*)d_in[17]; pa.W_pred = (const float*)d_in[19];
  pa.ws = ws; pa.inc = incraw;
  pa.p1e = wb + BO_W1TE; pa.p2e = wb + BO_W2TE;
  pa.p1n = wb + BO_W1TN; pa.p2n = wb + BO_W2TN;
  pa.pf = wb + BO_WFT;   pa.pp = wb + BO_WPT;
  pa.xg = wb + BO_XG;

  k_prep<<<488, 256, 0, stream>>>(pa);
  k_xrs2<<<512, 64, 0, stream>>>(wb + BO_XG, wb + BO_W1TE, n2e_b1, xrs);
  k_mlp96<<<EROWS/96, 256, 0, stream>>>(xrs, wb + BO_W2TE, n2e_b2, wb + BO_E2,
                                        ws + OFF_STATS_E, incraw);
  k_aggS<<<NROWS, 256, 0, stream>>>(wb + BO_E2, incraw, ws + OFF_STATS_E,
                                    n2e_g, n2e_be, wb + BO_NODES);
  k_n1<<<512, 64, 0, stream>>>(wb + BO_NODES, wb + BO_W1TN, e2n_b1, wb + BO_H1G);
  k_n2<<<512, 64, 0, stream>>>(wb + BO_H1G, wb + BO_W2TN, e2n_b2, wb + BO_M2,
                               ws + OFF_STATS_M);
  k_hf<<<512, 64, 0, stream>>>(wb + BO_XG, wb + BO_M2, ws + OFF_STATS_M,
                               e2n_g, e2n_be, wb + BO_WFT, b_fuse, wb + BO_FG);
  k_pred<<<64, 64, 0, stream>>>(wb + BO_FG, wb + BO_WPT, b_pred, centers,
                                (float*)d_out);
}